// Round 2
// baseline (195.336 us; speedup 1.0000x reference)
//
#include <hip/hip_runtime.h>
#include <hip/hip_bf16.h>

typedef float f32x4 __attribute__((ext_vector_type(4)));
typedef short bf16x8 __attribute__((ext_vector_type(8)));

#define HH 512
#define WW 512
#define NPLANES 48              // B*C = 16*3
#define KSIZE 23
#define NBLK (16 * 16 * NPLANES)
#define C1V 1.0e-4f             // 0.01^2
#define C2V 9.0e-4f             // 0.03^2

// LDS now holds ONLY the h-pass->v-pass transpose buffer:
// hb[ch][col][row], 4 channels x 32 cols x 64 rows bf16 = 16 KB.
// (round-13 change: SA/SB staging removed — each staged element fed exactly
// one h-pass fragment slot, i.e. zero LDS reuse; A/B frags now load straight
// from global. G moved to a precomputed 4 KB L2-resident workspace buffer.)
#define HB_CH 2048              // ushorts per channel (32 col * 64 row)

// XOR bank swizzle within a 64-row column; preserves 8-ushort (16B) blocks.
#define SWZ(rho, k) ((k) ^ (((rho) & 7) << 3))

// pack two fp32 -> bf16 pair (lo = a, hi = b), RNE (v_cvt_pk_bf16_f32)
__device__ __forceinline__ unsigned cvtpk(float a, float b) {
    union { __hip_bfloat162 h; unsigned u; } cv;
    cv.h = __float22bfloat162_rn(make_float2(a, b));
    return cv.u;
}

// From packed bf16 pairs a,b build packed ab and a^2+b^2 (fp32 math on the
// ROUNDED bf16 values -> numerics match the old bfmul path for ab; ss takes
// one rounding of a^2+b^2 instead of two).
__device__ __forceinline__ void prod2(unsigned a, unsigned b,
                                      unsigned& pab, unsigned& pss) {
    float al = __uint_as_float(a << 16), ah = __uint_as_float(a & 0xffff0000u);
    float bl = __uint_as_float(b << 16), bh = __uint_as_float(b & 0xffff0000u);
    pab = cvtpk(al * bl, ah * bh);
    pss = cvtpk(al * al + bl * bl, ah * ah + bh * bh);
}

__device__ __forceinline__ f32x4 mfma16(uint4 a, uint4 b, f32x4 c) {
    union { uint4 u; bf16x8 h; } ua, ub;
    ua.u = a; ub.u = b;
    return __builtin_amdgcn_mfma_f32_16x16x32_bf16(ua.h, ub.h, c, 0, 0, 0);
}

// ---- prep: build G (32 rows x 64 k, bf16 pairs) once into workspace ----
// G[r][k] = g[k-1-r] for k-1-r in [0,23), else 0; g = row-sums of the 2D
// normalized kernel (separable 1D tap).
__global__ __launch_bounds__(64) void ssim_prep_kernel(
    const float* __restrict__ w, unsigned* __restrict__ Gg)
{
    const int lane = threadIdx.x;
    float gv = 0.f;
    if (lane < KSIZE) {
        #pragma unroll
        for (int k = 0; k < KSIZE; ++k) gv += w[lane * KSIZE + k];
    }
    for (int idx = lane; idx < 32 * 32; idx += 64) {   // lane invariant per iter
        int r = idx >> 5, kd = idx & 31;
        int d0 = 2 * kd - 1 - r;
        float g0 = __shfl(gv, d0 & 63, 64);
        float g1 = __shfl(gv, (d0 + 1) & 63, 64);
        g0 = ((unsigned)d0 < (unsigned)KSIZE) ? g0 : 0.f;
        g1 = ((unsigned)(d0 + 1) < (unsigned)KSIZE) ? g1 : 0.f;
        Gg[idx] = cvtpk(g0, g1);
    }
}

// launch_bounds (256,6): VGPR cap 85. Live set estimate ~75-83 (acc 32 +
// 2-ks loads 32 + frags/addr). Round-12's spill was at cap ~85 with the OLD
// 5-channel + staging-register kernel (~95 live); the new set is smaller.
// If VGPR_Count shows scratch, drop to (256,5).
__global__ __launch_bounds__(256, 6) void ssim_main_kernel(
    const float* __restrict__ in, const float* __restrict__ tg,
    const unsigned* __restrict__ Gg, float* __restrict__ partial)
{
    __shared__ __align__(16) unsigned short hb[4 * HB_CH];   // 16 KB
    __shared__ float swsum[4];

    const int tid = threadIdx.x;
    const int wave = tid >> 6, lane = tid & 63;
    const int m = lane & 15, q = lane >> 4;

    const int blk = blockIdx.x;
    const int plane = blk >> 8;
    const int t2 = blk & 255;
    const int x0 = (t2 & 15) * 32 - 12;   // frame origin (16B-aligned cols)
    const int y0 = (t2 >> 4) * 32 - 12;
    const float* __restrict__ inp = in + (size_t)plane * (HH * WW);
    const float* __restrict__ tgp = tg + (size_t)plane * (HH * WW);

    // h-pass: wave owns frame rows wave*16 .. +15 (M dim); rows 55..63 are
    // junk that v-pass multiplies by exact-zero G taps — but loads must stay
    // in-bounds, so OOB rows produce zeros (finite, harmless).
    const int row = y0 + wave * 16 + m;
    const bool rowOK = ((unsigned)row < (unsigned)HH);
    const bool xin = (x0 >= 0) && (x0 + 64 <= WW);   // block-uniform

    f32x4 acc[4][2];
    const f32x4 zz = {0.f, 0.f, 0.f, 0.f};
    #pragma unroll
    for (int ch = 0; ch < 4; ++ch) { acc[ch][0] = zz; acc[ch][1] = zz; }

    // ---- h-pass (MFMA), A/B frags straight from global, G from L2 ----
    #pragma unroll
    for (int ks = 0; ks < 2; ++ks) {
        const int cb = x0 + ks * 32 + q * 8;   // frame col base, mult of 4
        float4 z4; z4.x = z4.y = z4.z = z4.w = 0.f;
        float4 fa0 = z4, fa1 = z4, fb0 = z4, fb1 = z4;
        if (xin) {
            if (rowOK) {
                const float* ri = inp + row * WW + cb;
                const float* rt = tgp + row * WW + cb;
                fa0 = ((const float4*)ri)[0]; fa1 = ((const float4*)ri)[1];
                fb0 = ((const float4*)rt)[0]; fb1 = ((const float4*)rt)[1];
            }
        } else if (rowOK) {
            // x-edge tiles: float4s never straddle the boundary (all offsets
            // multiples of 4), so whole-float4 predication is exact zero-pad.
            const float* ri = inp + row * WW;
            const float* rt = tgp + row * WW;
            if (cb >= 0 && cb + 4 <= WW) {
                fa0 = *(const float4*)(ri + cb);     fb0 = *(const float4*)(rt + cb);
            }
            if (cb + 4 >= 0 && cb + 8 <= WW) {
                fa1 = *(const float4*)(ri + cb + 4); fb1 = *(const float4*)(rt + cb + 4);
            }
        }
        // 4 channels: a, b, a^2+b^2 (folded sigma channel), a*b
        uint4 ua, ub, uab, uss;
        ua.x = cvtpk(fa0.x, fa0.y); ua.y = cvtpk(fa0.z, fa0.w);
        ua.z = cvtpk(fa1.x, fa1.y); ua.w = cvtpk(fa1.z, fa1.w);
        ub.x = cvtpk(fb0.x, fb0.y); ub.y = cvtpk(fb0.z, fb0.w);
        ub.z = cvtpk(fb1.x, fb1.y); ub.w = cvtpk(fb1.z, fb1.w);
        prod2(ua.x, ub.x, uab.x, uss.x);
        prod2(ua.y, ub.y, uab.y, uss.y);
        prod2(ua.z, ub.z, uab.z, uss.z);
        prod2(ua.w, ub.w, uab.w, uss.w);
        #pragma unroll
        for (int nc = 0; nc < 2; ++nc) {
            uint4 gf = *(const uint4*)(Gg + (nc * 16 + m) * 32 + ks * 16 + q * 4);
            acc[0][nc] = mfma16(ua,  gf, acc[0][nc]);
            acc[1][nc] = mfma16(ub,  gf, acc[1][nc]);
            acc[2][nc] = mfma16(uss, gf, acc[2][nc]);
            acc[3][nc] = mfma16(uab, gf, acc[3][nc]);
        }
    }

    // D frag: col = lane&15 (+nc*16), row = q*4 + reg (+wave*16). hb[ch][col][row].
    #pragma unroll
    for (int ch = 0; ch < 4; ++ch)
        #pragma unroll
        for (int nc = 0; nc < 2; ++nc) {
            f32x4 a = acc[ch][nc];
            uint2 pk;
            pk.x = cvtpk(a[0], a[1]);
            pk.y = cvtpk(a[2], a[3]);
            const int col = nc * 16 + m;
            const int rb = wave * 16 + q * 4;
            *(uint2*)&hb[ch * HB_CH + col * 64 + SWZ(col, rb)] = pk;
        }
    __syncthreads();   // the kernel's only data barrier

    // ---- v-pass (MFMA): wave = output quadrant (mrow, nc2) ----
    const int mrow = wave >> 1, nc2 = wave & 1;
    f32x4 av[4];
    #pragma unroll
    for (int ch = 0; ch < 4; ++ch) av[ch] = zz;

    #pragma unroll
    for (int ks = 0; ks < 2; ++ks) {
        uint4 ga = *(const uint4*)(Gg + (mrow * 16 + m) * 32 + ks * 16 + q * 4);
        #pragma unroll
        for (int ch = 0; ch < 4; ++ch) {
            const int col = nc2 * 16 + m;
            uint4 ub = *(const uint4*)&hb[ch * HB_CH + col * 64 + SWZ(col, ks * 32 + q * 8)];
            av[ch] = mfma16(ga, ub, av[ch]);
        }
    }

    // ---- SSIM map on 4 px/lane + reduction ----
    float lsum = 0.f;
    #pragma unroll
    for (int i = 0; i < 4; ++i) {
        float vx = av[0][i], vt = av[1][i];
        float vss = av[2][i], vxt = av[3][i];
        float m1s = vx * vx, m2s = vt * vt, m12 = vx * vt;
        float sss = vss - m1s - m2s;          // s1 + s2
        float s12 = vxt - m12;
        float num = (2.f * m12 + C1V) * (2.f * s12 + C2V);
        float den = (m1s + m2s + C1V) * (sss + C2V);
        lsum += num * __builtin_amdgcn_rcpf(den);   // den > 0 for this data
    }
    #pragma unroll
    for (int off = 32; off > 0; off >>= 1)
        lsum += __shfl_down(lsum, off, 64);
    if (lane == 0) swsum[wave] = lsum;
    __syncthreads();
    if (tid == 0)
        partial[blk] = swsum[0] + swsum[1] + swsum[2] + swsum[3];
}

__global__ __launch_bounds__(256) void ssim_final_kernel(
    const float* __restrict__ partial, float* __restrict__ out)
{
    __shared__ float swsum[4];
    const int tid = threadIdx.x;
    float s = 0.f;
    const float4* p4 = (const float4*)partial;
    for (int i = tid; i < NBLK / 4; i += 256) {
        float4 v = p4[i];
        s += (v.x + v.y) + (v.z + v.w);
    }
    #pragma unroll
    for (int off = 32; off > 0; off >>= 1)
        s += __shfl_down(s, off, 64);
    if ((tid & 63) == 0) swsum[tid >> 6] = s;
    __syncthreads();
    if (tid == 0)
        out[0] = 1.0f - (swsum[0] + swsum[1] + swsum[2] + swsum[3])
                        * (1.0f / ((float)NPLANES * HH * WW));
}

extern "C" void kernel_launch(void* const* d_in, const int* in_sizes, int n_in,
                              void* d_out, int out_size, void* d_ws, size_t ws_size,
                              hipStream_t stream) {
    const float* inp = (const float*)d_in[0];
    const float* tgt = (const float*)d_in[1];
    const float* wgt = (const float*)d_in[2];
    float* out = (float*)d_out;
    float* partial = (float*)d_ws;                       // NBLK floats
    unsigned* Gg = (unsigned*)((char*)d_ws + NBLK * sizeof(float));  // 4 KB G

    ssim_prep_kernel<<<1, 64, 0, stream>>>(wgt, Gg);
    ssim_main_kernel<<<NBLK, 256, 0, stream>>>(inp, tgt, Gg, partial);
    ssim_final_kernel<<<1, 256, 0, stream>>>(partial, out);
}

// Round 3
// 157.481 us; speedup vs baseline: 1.2404x; 1.2404x over previous
//
#include <hip/hip_runtime.h>
#include <hip/hip_bf16.h>

typedef float f32x4 __attribute__((ext_vector_type(4)));
typedef short bf16x8 __attribute__((ext_vector_type(8)));

#define HH 512
#define WW 512
#define NPLANES 48              // B*C = 16*3
#define KSIZE 23
#define NBLK (16 * 16 * NPLANES)
#define C1V 1.0e-4f             // 0.01^2
#define C2V 9.0e-4f             // 0.03^2

// LDS layout (ushort indices), ALIASED across phases:
//   stage:  SB [0,3960) SA [3960,7920) rows 0..54, pitch 72
//           OV [7920,8568) zero-filled (SA h-pass overflow rows 55..63 land
//           here; SB overflow lands in SA — finite always)
//           G  [8568,10616) 32x64 bf16, dword-swizzled copy of prep buffer
//   h->v:   HB [0,8192) aliases SA/SB AFTER barrier2 (post h-pass reads);
//           G region is never aliased (v-pass reads it too).
// Total 10616 ushorts = 21232 B -> LDS allows 7 blocks/CU; VGPR cap (256,6)
// makes it 6 (24 waves/CU = 75% occupancy) vs round-1's 16.9 KB/63%.
#define SB_O   0
#define SA_O   3960
#define OV_O   7920
#define G_O    8568
#define HB_O   0
#define HB_CH  2048
#define SPITCH 72
#define LDS_TOT 10616

// XOR bank swizzle within a pitch-64 region; preserves 8-ushort (16B) blocks.
#define SWZ(rho, k) ((k) ^ (((rho) & 7) << 3))

// pack two fp32 -> bf16 pair (lo = a, hi = b), RNE (v_cvt_pk_bf16_f32)
__device__ __forceinline__ unsigned cvtpk(float a, float b) {
    union { __hip_bfloat162 h; unsigned u; } cv;
    cv.h = __float22bfloat162_rn(make_float2(a, b));
    return cv.u;
}

// From packed bf16 pairs a,b build packed ab and a^2+b^2 (fp32 math on the
// ROUNDED bf16 values; ss takes one rounding of a^2+b^2 instead of two).
__device__ __forceinline__ void prod2(unsigned a, unsigned b,
                                      unsigned& pab, unsigned& pss) {
    float al = __uint_as_float(a << 16), ah = __uint_as_float(a & 0xffff0000u);
    float bl = __uint_as_float(b << 16), bh = __uint_as_float(b & 0xffff0000u);
    pab = cvtpk(al * bl, ah * bh);
    pss = cvtpk(al * al + bl * bl, ah * ah + bh * bh);
}

__device__ __forceinline__ f32x4 mfma16(uint4 a, uint4 b, f32x4 c) {
    union { uint4 u; bf16x8 h; } ua, ub;
    ua.u = a; ub.u = b;
    return __builtin_amdgcn_mfma_f32_16x16x32_bf16(ua.h, ub.h, c, 0, 0, 0);
}

// ---- prep: build G (32 rows x 64 k, bf16 pairs, LINEAR layout) once ----
// G[r][k] = g[k-1-r] for k-1-r in [0,23), else 0; g = row-sums of the 2D
// normalized kernel (separable 1D tap).
__global__ __launch_bounds__(64) void ssim_prep_kernel(
    const float* __restrict__ w, unsigned* __restrict__ Gg)
{
    const int lane = threadIdx.x;
    float gv = 0.f;
    if (lane < KSIZE) {
        #pragma unroll
        for (int k = 0; k < KSIZE; ++k) gv += w[lane * KSIZE + k];
    }
    for (int idx = lane; idx < 32 * 32; idx += 64) {
        int r = idx >> 5, kd = idx & 31;
        int d0 = 2 * kd - 1 - r;
        float g0 = __shfl(gv, d0 & 63, 64);
        float g1 = __shfl(gv, (d0 + 1) & 63, 64);
        g0 = ((unsigned)d0 < (unsigned)KSIZE) ? g0 : 0.f;
        g1 = ((unsigned)(d0 + 1) < (unsigned)KSIZE) ? g1 : 0.f;
        Gg[idx] = cvtpk(g0, g1);
    }
}

// (256,6): VGPR cap 85. Live set ~70 (acc 32 + stage-load 32 non-overlapping
// lifetimes + frags/addr). If VGPR_Count shows scratch, drop to (256,5).
__global__ __launch_bounds__(256, 6) void ssim_main_kernel(
    const float* __restrict__ in, const float* __restrict__ tg,
    const unsigned* __restrict__ Gg, float* __restrict__ partial)
{
    __shared__ __align__(16) unsigned short lds[LDS_TOT];
    __shared__ float swsum[4];

    const int tid = threadIdx.x;
    const int wave = tid >> 6, lane = tid & 63;
    const int m = lane & 15, q = lane >> 4;

    const int blk = blockIdx.x;
    const int plane = blk >> 8;
    const int t2 = blk & 255;
    const int x0 = (t2 & 15) * 32 - 12;   // 16B-aligned frame origin
    const int y0 = (t2 >> 4) * 32 - 12;
    const float* __restrict__ inp = in + (size_t)plane * (HH * WW);
    const float* __restrict__ tgp = tg + (size_t)plane * (HH * WW);

    const bool interior = (x0 >= 0) && (y0 >= 0) && (x0 + 64 <= WW) && (y0 + 55 <= HH);

    // ---- phase A: ISSUE staging loads first (coalesced; latency hidden
    //      under the G-copy / OV-fill below). 55 rows x 8 col-groups = 440
    //      tasks; thread handles tid and tid+256.
    float4 La[2][2], Lb[2][2];
    if (interior) {
        #pragma unroll
        for (int it = 0; it < 2; ++it) {
            int t = tid + it * 256;
            if (t < 440) {
                int r = t >> 3, c8 = (t & 7) << 3;
                const float4* pa = (const float4*)(inp + (y0 + r) * WW + x0 + c8);
                const float4* pb = (const float4*)(tgp + (y0 + r) * WW + x0 + c8);
                La[it][0] = pa[0]; La[it][1] = pa[1];
                Lb[it][0] = pb[0]; Lb[it][1] = pb[1];
            }
        }
    }

    // ---- phase B: copy G into LDS (swizzled) + zero-fill overflow strip ----
    {   // 256 threads x 1 uint4 = 1024 dwords = whole G
        int r = tid >> 3;                    // 0..31
        int dc = (tid & 7) << 2;             // dword col, multiple of 4
        uint4 g4 = *(const uint4*)(Gg + r * 32 + dc);
        *(uint4*)&lds[G_O + r * 64 + (((dc << 1)) ^ ((r & 7) << 3))] = g4;
    }
    if (tid < 81) {
        uint4 z; z.x = z.y = z.z = z.w = 0u;
        *(uint4*)&lds[OV_O + tid * 8] = z;
    }

    // ---- phase C: consume staging loads -> bf16 LDS ----
    if (interior) {
        #pragma unroll
        for (int it = 0; it < 2; ++it) {
            int t = tid + it * 256;
            if (t < 440) {
                int r = t >> 3, c8 = (t & 7) << 3;
                uint4 va, vb;
                va.x = cvtpk(La[it][0].x, La[it][0].y); va.y = cvtpk(La[it][0].z, La[it][0].w);
                va.z = cvtpk(La[it][1].x, La[it][1].y); va.w = cvtpk(La[it][1].z, La[it][1].w);
                vb.x = cvtpk(Lb[it][0].x, Lb[it][0].y); vb.y = cvtpk(Lb[it][0].z, Lb[it][0].w);
                vb.z = cvtpk(Lb[it][1].x, Lb[it][1].y); vb.w = cvtpk(Lb[it][1].z, Lb[it][1].w);
                *(uint4*)&lds[SA_O + r * SPITCH + c8] = va;
                *(uint4*)&lds[SB_O + r * SPITCH + c8] = vb;
            }
        }
    } else {
        unsigned* ldsw = (unsigned*)lds;
        for (int t = tid; t < 55 * 32; t += 256) {
            int r = t >> 5, cd = t & 31;
            int gy = y0 + r, gx = x0 + cd * 2;
            float a0 = 0.f, a1 = 0.f, b0 = 0.f, b1 = 0.f;
            if (gy >= 0 && gy < HH) {
                const float* ri = inp + gy * WW;
                const float* rt = tgp + gy * WW;
                if ((unsigned)gx < (unsigned)WW)       { a0 = ri[gx];     b0 = rt[gx]; }
                if ((unsigned)(gx + 1) < (unsigned)WW) { a1 = ri[gx + 1]; b1 = rt[gx + 1]; }
            }
            ldsw[(SA_O >> 1) + r * 36 + cd] = cvtpk(a0, a1);
            ldsw[(SB_O >> 1) + r * 36 + cd] = cvtpk(b0, b1);
        }
    }
    __syncthreads();   // barrier1: staging + G + OV visible

    // ---- h-pass (MFMA): wave = M-tile (frame rows wave*16..+15). Rows
    //      55..63 read OV zeros / SA junk — finite, killed by zero G taps.
    f32x4 acc[4][2];
    const f32x4 zz = {0.f, 0.f, 0.f, 0.f};
    #pragma unroll
    for (int ch = 0; ch < 4; ++ch) { acc[ch][0] = zz; acc[ch][1] = zz; }

    #pragma unroll
    for (int ks = 0; ks < 2; ++ks) {
        const int off = (wave * 16 + m) * SPITCH + ks * 32 + q * 8;
        uint4 ua = *(const uint4*)&lds[SA_O + off];
        uint4 ub = *(const uint4*)&lds[SB_O + off];
        uint4 uab, uss;
        prod2(ua.x, ub.x, uab.x, uss.x);
        prod2(ua.y, ub.y, uab.y, uss.y);
        prod2(ua.z, ub.z, uab.z, uss.z);
        prod2(ua.w, ub.w, uab.w, uss.w);
        #pragma unroll
        for (int nc = 0; nc < 2; ++nc) {
            const int gr = nc * 16 + m;
            uint4 gf = *(const uint4*)&lds[G_O + gr * 64 + SWZ(gr, ks * 32 + q * 8)];
            acc[0][nc] = mfma16(ua,  gf, acc[0][nc]);
            acc[1][nc] = mfma16(ub,  gf, acc[1][nc]);
            acc[2][nc] = mfma16(uss, gf, acc[2][nc]);
            acc[3][nc] = mfma16(uab, gf, acc[3][nc]);
        }
    }
    __syncthreads();   // barrier2: all SA/SB reads done -> HB may alias them

    // D frag: col = lane&15 (+nc*16), row = q*4 + reg (+wave*16). hb[ch][col][row].
    #pragma unroll
    for (int ch = 0; ch < 4; ++ch)
        #pragma unroll
        for (int nc = 0; nc < 2; ++nc) {
            f32x4 a = acc[ch][nc];
            uint2 pk;
            pk.x = cvtpk(a[0], a[1]);
            pk.y = cvtpk(a[2], a[3]);
            const int col = nc * 16 + m;
            const int rb = wave * 16 + q * 4;
            *(uint2*)&lds[HB_O + ch * HB_CH + col * 64 + SWZ(col, rb)] = pk;
        }
    __syncthreads();   // barrier3: HB visible

    // ---- v-pass (MFMA): wave = output quadrant (mrow, nc2) ----
    const int mrow = wave >> 1, nc2 = wave & 1;
    f32x4 av[4];
    #pragma unroll
    for (int ch = 0; ch < 4; ++ch) av[ch] = zz;

    #pragma unroll
    for (int ks = 0; ks < 2; ++ks) {
        const int ar = mrow * 16 + m;
        uint4 ga = *(const uint4*)&lds[G_O + ar * 64 + SWZ(ar, ks * 32 + q * 8)];
        #pragma unroll
        for (int ch = 0; ch < 4; ++ch) {
            const int col = nc2 * 16 + m;
            uint4 ub = *(const uint4*)&lds[HB_O + ch * HB_CH + col * 64 + SWZ(col, ks * 32 + q * 8)];
            av[ch] = mfma16(ga, ub, av[ch]);
        }
    }

    // ---- SSIM map on 4 px/lane + reduction ----
    float lsum = 0.f;
    #pragma unroll
    for (int i = 0; i < 4; ++i) {
        float vx = av[0][i], vt = av[1][i];
        float vss = av[2][i], vxt = av[3][i];
        float m1s = vx * vx, m2s = vt * vt, m12 = vx * vt;
        float sss = vss - m1s - m2s;          // s1 + s2
        float s12 = vxt - m12;
        float num = (2.f * m12 + C1V) * (2.f * s12 + C2V);
        float den = (m1s + m2s + C1V) * (sss + C2V);
        lsum += num * __builtin_amdgcn_rcpf(den);   // den > 0 for this data
    }
    #pragma unroll
    for (int off = 32; off > 0; off >>= 1)
        lsum += __shfl_down(lsum, off, 64);
    if (lane == 0) swsum[wave] = lsum;
    __syncthreads();
    if (tid == 0)
        partial[blk] = swsum[0] + swsum[1] + swsum[2] + swsum[3];
}

__global__ __launch_bounds__(256) void ssim_final_kernel(
    const float* __restrict__ partial, float* __restrict__ out)
{
    __shared__ float swsum[4];
    const int tid = threadIdx.x;
    float s = 0.f;
    const float4* p4 = (const float4*)partial;
    for (int i = tid; i < NBLK / 4; i += 256) {
        float4 v = p4[i];
        s += (v.x + v.y) + (v.z + v.w);
    }
    #pragma unroll
    for (int off = 32; off > 0; off >>= 1)
        s += __shfl_down(s, off, 64);
    if ((tid & 63) == 0) swsum[tid >> 6] = s;
    __syncthreads();
    if (tid == 0)
        out[0] = 1.0f - (swsum[0] + swsum[1] + swsum[2] + swsum[3])
                        * (1.0f / ((float)NPLANES * HH * WW));
}

extern "C" void kernel_launch(void* const* d_in, const int* in_sizes, int n_in,
                              void* d_out, int out_size, void* d_ws, size_t ws_size,
                              hipStream_t stream) {
    const float* inp = (const float*)d_in[0];
    const float* tgt = (const float*)d_in[1];
    const float* wgt = (const float*)d_in[2];
    float* out = (float*)d_out;
    float* partial = (float*)d_ws;                       // NBLK floats
    unsigned* Gg = (unsigned*)((char*)d_ws + NBLK * sizeof(float));  // 4 KB G

    ssim_prep_kernel<<<1, 64, 0, stream>>>(wgt, Gg);
    ssim_main_kernel<<<NBLK, 256, 0, stream>>>(inp, tgt, Gg, partial);
    ssim_final_kernel<<<1, 256, 0, stream>>>(partial, out);
}